// Round 1
// baseline (2987.112 us; speedup 1.0000x reference)
//
#include <hip/hip_runtime.h>
#include <hip/hip_bf16.h>
#include <math.h>
#include <cstdint>

static constexpr int NN = 50000;   // nodes
static constexpr int NE = 400000;  // edges
static constexpr int MF = 4;       // input feature dim
static constexpr int H  = 400;     // hidden dim
static constexpr int NG = 128;     // graphs
static constexpr int NC = 10;      // classes
static constexpr float EPS = 1e-5f;

// ---------------- CSR build ----------------

__global__ void k_count(const int* __restrict__ dst, int* __restrict__ deg) {
    int e = blockIdx.x * blockDim.x + threadIdx.x;
    if (e < NE) atomicAdd(&deg[dst[e]], 1);
}

__global__ void k_scan(const int* __restrict__ deg, int* __restrict__ rowp) {
    __shared__ int sd[1024];
    __shared__ int srun;
    int t = threadIdx.x;
    if (t == 0) { srun = 0; rowp[0] = 0; }
    __syncthreads();
    for (int base = 0; base < NN; base += 1024) {
        int v = (base + t < NN) ? deg[base + t] : 0;
        sd[t] = v;
        __syncthreads();
        for (int off = 1; off < 1024; off <<= 1) {
            int x = (t >= off) ? sd[t - off] : 0;
            __syncthreads();
            sd[t] += x;
            __syncthreads();
        }
        if (base + t < NN) rowp[base + t + 1] = srun + sd[t];
        __syncthreads();
        if (t == 0) srun += sd[1023];
        __syncthreads();
    }
}

__global__ void k_scatter(const int* __restrict__ src, const int* __restrict__ dst,
                          int* __restrict__ cur, int* __restrict__ csrc) {
    int e = blockIdx.x * blockDim.x + threadIdx.x;
    if (e < NE) {
        int d = dst[e];
        int p = atomicAdd(&cur[d], 1);
        csrc[p] = src[e];
    }
}

// ---------------- aggregation ----------------

// first layer: gather x rows (4 floats each)
__global__ void k_agg0(const float* __restrict__ x, const int* __restrict__ rowp,
                       const int* __restrict__ csrc, float* __restrict__ out) {
    int n = blockIdx.x * blockDim.x + threadIdx.x;
    if (n >= NN) return;
    float4 acc = make_float4(0.f, 0.f, 0.f, 0.f);
    int b = rowp[n], e = rowp[n + 1];
    for (int p = b; p < e; ++p) {
        float4 v = ((const float4*)x)[csrc[p]];
        acc.x += v.x; acc.y += v.y; acc.z += v.z; acc.w += v.w;
    }
    ((float4*)out)[n] = acc;
}

// hidden layers: one block per node, 400 features over 256 lanes
__global__ __launch_bounds__(256) void k_aggH(const float* __restrict__ h,
                                              const int* __restrict__ rowp,
                                              const int* __restrict__ csrc,
                                              float* __restrict__ out) {
    int n = blockIdx.x;
    int t = threadIdx.x;
    int b = rowp[n], e = rowp[n + 1];
    float a0 = 0.f, a1 = 0.f;
    for (int p = b; p < e; ++p) {
        const float* r = h + (long)csrc[p] * H;
        a0 += r[t];
        if (t < H - 256) a1 += r[256 + t];
    }
    out[(long)n * H + t] = a0;
    if (t < H - 256) out[(long)n * H + 256 + t] = a1;
}

// ---------------- first linear (K = 4) ----------------

__global__ void k_lin0(const float* __restrict__ a4, const float* __restrict__ w,
                       const float* __restrict__ b, float* __restrict__ out) {
    long i = (long)blockIdx.x * blockDim.x + threadIdx.x;
    if (i >= (long)NN * H) return;
    int n = (int)(i / H), j = (int)(i - (long)n * H);
    float4 av = ((const float4*)a4)[n];
    float4 wv = ((const float4*)w)[j];
    out[i] = fmaf(av.x, wv.x, fmaf(av.y, wv.y, fmaf(av.z, wv.z, av.w * wv.w))) + b[j];
}

// ---------------- BN stats ----------------

__global__ __launch_bounds__(256) void k_stats(const float* __restrict__ z,
                                               float* __restrict__ stats) {
    int t = threadIdx.x;
    float s0 = 0.f, q0 = 0.f, s1 = 0.f, q1 = 0.f;
    for (int r = blockIdx.x; r < NN; r += gridDim.x) {
        const float* row = z + (long)r * H;
        float v = row[t];
        s0 += v; q0 += v * v;
        if (t < H - 256) {
            float u = row[256 + t];
            s1 += u; q1 += u * u;
        }
    }
    atomicAdd(&stats[t], s0);
    atomicAdd(&stats[H + t], q0);
    if (t < H - 256) {
        atomicAdd(&stats[256 + t], s1);
        atomicAdd(&stats[H + 256 + t], q1);
    }
}

__global__ void k_finalize(float* __restrict__ stats, const float* __restrict__ g,
                           const float* __restrict__ be, float* __restrict__ scale,
                           float* __restrict__ shift) {
    int j = blockIdx.x * blockDim.x + threadIdx.x;
    if (j >= H) return;
    float m = stats[j] / NN;
    float v = stats[H + j] / NN - m * m;
    v = fmaxf(v, 0.f);
    float rs = rsqrtf(v + EPS);
    float sc = g[j] * rs;
    scale[j] = sc;
    shift[j] = be[j] - m * sc;
    stats[j] = 0.f;          // self-clean for next use
    stats[H + j] = 0.f;
}

// ---------------- GEMM: out[n][k] = sum_j f(A[n][j]) * W[k][j] + bias[k] ----------------
// f = relu(a*scale[j]+shift[j]) when TRANS, identity otherwise.
// A: M x 400 row-major, W: 400 x 400 row-major. Tiles 64x64x16, 256 threads, 4x4 micro.

template <bool TRANS>
__global__ __launch_bounds__(256) void gemm400(const float* __restrict__ A,
                                               const float* __restrict__ W,
                                               const float* __restrict__ bias,
                                               const float* __restrict__ scale,
                                               const float* __restrict__ shift,
                                               float* __restrict__ out, int M) {
    constexpr int BM = 64, BN = 64, BK = 16, LDT = 68;
    __shared__ __align__(16) float As[BK][LDT];
    __shared__ __align__(16) float Bs[BK][LDT];
    int bm = blockIdx.x * BM;
    int bn = blockIdx.y * BN;
    int t = threadIdx.x;
    int tx = t & 15, ty = t >> 4;
    int lr = t >> 2;            // 0..63: tile row (A: node, B: out-feature)
    int lc = (t & 3) * 4;       // 0,4,8,12: k offset within tile

    float acc[4][4] = {};
    for (int k0 = 0; k0 < 400; k0 += BK) {
        // A tile
        {
            int n = bm + lr;
            float4 v = make_float4(0.f, 0.f, 0.f, 0.f);
            if (n < M) v = *(const float4*)(A + (long)n * 400 + k0 + lc);
            if (TRANS) {
                float4 sc = *(const float4*)(scale + k0 + lc);
                float4 sh = *(const float4*)(shift + k0 + lc);
                v.x = fmaxf(fmaf(v.x, sc.x, sh.x), 0.f);
                v.y = fmaxf(fmaf(v.y, sc.y, sh.y), 0.f);
                v.z = fmaxf(fmaf(v.z, sc.z, sh.z), 0.f);
                v.w = fmaxf(fmaf(v.w, sc.w, sh.w), 0.f);
            }
            As[lc + 0][lr] = v.x; As[lc + 1][lr] = v.y;
            As[lc + 2][lr] = v.z; As[lc + 3][lr] = v.w;
        }
        // B tile
        {
            int k = bn + lr;
            float4 v = make_float4(0.f, 0.f, 0.f, 0.f);
            if (k < 400) v = *(const float4*)(W + (long)k * 400 + k0 + lc);
            Bs[lc + 0][lr] = v.x; Bs[lc + 1][lr] = v.y;
            Bs[lc + 2][lr] = v.z; Bs[lc + 3][lr] = v.w;
        }
        __syncthreads();
#pragma unroll
        for (int kk = 0; kk < BK; ++kk) {
            float4 av = *(const float4*)&As[kk][ty * 4];
            float4 bv = *(const float4*)&Bs[kk][tx * 4];
            float a[4] = {av.x, av.y, av.z, av.w};
            float b[4] = {bv.x, bv.y, bv.z, bv.w};
#pragma unroll
            for (int i = 0; i < 4; ++i)
#pragma unroll
                for (int j = 0; j < 4; ++j)
                    acc[i][j] = fmaf(a[i], b[j], acc[i][j]);
        }
        __syncthreads();
    }
#pragma unroll
    for (int i = 0; i < 4; ++i) {
        int n = bm + ty * 4 + i;
        if (n >= M) continue;
#pragma unroll
        for (int j = 0; j < 4; ++j) {
            int k = bn + tx * 4 + j;
            if (k < 400) out[(long)n * 400 + k] = acc[i][j] + bias[k];
        }
    }
}

// ---------------- pooling (batch is sorted) ----------------

__global__ __launch_bounds__(256) void k_pool(const float* __restrict__ h,
                                              const int* __restrict__ batch,
                                              float* __restrict__ pools, int off) {
    int t = threadIdx.x;
    int rows = (NN + gridDim.x - 1) / gridDim.x;
    int r0 = blockIdx.x * rows;
    int r1 = min(r0 + rows, NN);
    if (r0 >= r1) return;
    float a0 = 0.f, a1 = 0.f;
    int gp = batch[r0];
    for (int r = r0; r < r1; ++r) {
        int gg = batch[r];
        if (gg != gp) {
            atomicAdd(&pools[(long)gp * (3 * H) + off + t], a0);
            if (t < H - 256) atomicAdd(&pools[(long)gp * (3 * H) + off + 256 + t], a1);
            a0 = 0.f; a1 = 0.f; gp = gg;
        }
        const float* row = h + (long)r * H;
        a0 += row[t];
        if (t < H - 256) a1 += row[256 + t];
    }
    atomicAdd(&pools[(long)gp * (3 * H) + off + t], a0);
    if (t < H - 256) atomicAdd(&pools[(long)gp * (3 * H) + off + 256 + t], a1);
}

// ---------------- readout head ----------------

__global__ __launch_bounds__(256) void k_head(const float* __restrict__ pools,
                                              const float* __restrict__ w1,
                                              const float* __restrict__ b1,
                                              const float* __restrict__ w2,
                                              const float* __restrict__ b2,
                                              float* __restrict__ out) {
    __shared__ float xg[1200];
    __shared__ float zz[600];
    __shared__ float lg[16];
    int g = blockIdx.x, t = threadIdx.x;
    for (int i = t; i < 1200; i += 256) xg[i] = pools[(long)g * 1200 + i];
    __syncthreads();
    for (int j = t; j < 600; j += 256) {
        float s = b1[j];
        const float* wr = w1 + (long)j * 1200;
        for (int k = 0; k < 1200; k += 4) {
            s = fmaf(xg[k], wr[k], s);
            s = fmaf(xg[k + 1], wr[k + 1], s);
            s = fmaf(xg[k + 2], wr[k + 2], s);
            s = fmaf(xg[k + 3], wr[k + 3], s);
        }
        zz[j] = fmaxf(s, 0.f);
    }
    __syncthreads();
    if (t < NC) {
        float s = b2[t];
        const float* wr = w2 + t * 600;
        for (int k = 0; k < 600; ++k) s = fmaf(zz[k], wr[k], s);
        lg[t] = s;
    }
    __syncthreads();
    if (t == 0) {
        float mx = lg[0];
        for (int c = 1; c < NC; ++c) mx = fmaxf(mx, lg[c]);
        float se = 0.f;
        for (int c = 0; c < NC; ++c) se += expf(lg[c] - mx);
        float l = logf(se);
        for (int c = 0; c < NC; ++c) out[(long)g * NC + c] = lg[c] - mx - l;
    }
}

// ---------------- launch ----------------

extern "C" void kernel_launch(void* const* d_in, const int* in_sizes, int n_in,
                              void* d_out, int out_size, void* d_ws, size_t ws_size,
                              hipStream_t stream) {
    const float* x      = (const float*)d_in[0];
    const int*   ei     = (const int*)d_in[1];
    const int*   batch  = (const int*)d_in[2];
    const float* c0_w1  = (const float*)d_in[4];
    const float* c0_b1  = (const float*)d_in[5];
    const float* c0_g1  = (const float*)d_in[6];
    const float* c0_be1 = (const float*)d_in[7];
    const float* c0_w2  = (const float*)d_in[8];
    const float* c0_b2  = (const float*)d_in[9];
    const float* c0_g2  = (const float*)d_in[10];
    const float* c0_be2 = (const float*)d_in[11];
    const float* c0_w3  = (const float*)d_in[12];
    const float* c0_b3  = (const float*)d_in[13];
    const float* cw1    = (const float*)d_in[14];
    const float* cb1    = (const float*)d_in[15];
    const float* cg1    = (const float*)d_in[16];
    const float* cbe1   = (const float*)d_in[17];
    const float* cw2    = (const float*)d_in[18];
    const float* cb2    = (const float*)d_in[19];
    const float* cg2    = (const float*)d_in[20];
    const float* cbe2   = (const float*)d_in[21];
    const float* cw3    = (const float*)d_in[22];
    const float* cb3    = (const float*)d_in[23];
    const float* lin1_w = (const float*)d_in[24];
    const float* lin1_b = (const float*)d_in[25];
    const float* lin2_w = (const float*)d_in[26];
    const float* lin2_b = (const float*)d_in[27];

    const int* src = ei;
    const int* dst = ei + NE;

    char* ws = (char*)d_ws;
    size_t off = 0;
    auto alloc = [&](size_t bytes) {
        void* p = ws + off;
        off += (bytes + 255) & ~(size_t)255;
        return p;
    };
    float* bufh  = (float*)alloc((size_t)NN * H * 4);
    float* bufa  = (float*)alloc((size_t)NN * H * 4);
    float* agg0  = (float*)alloc((size_t)NN * MF * 4);
    float* stats = (float*)alloc(2 * H * 4);
    float* scale = (float*)alloc(H * 4);
    float* shift = (float*)alloc(H * 4);
    float* pools = (float*)alloc((size_t)NG * 3 * H * 4);
    int*   deg   = (int*)alloc((size_t)NN * 4);
    int*   rowp  = (int*)alloc((size_t)(NN + 1) * 4);
    int*   cur   = (int*)alloc((size_t)NN * 4);
    int*   csrc  = (int*)alloc((size_t)NE * 4);

    hipMemsetAsync(deg, 0, (size_t)NN * 4, stream);
    hipMemsetAsync(stats, 0, 2 * H * 4, stream);
    hipMemsetAsync(pools, 0, (size_t)NG * 3 * H * 4, stream);

    // CSR build
    k_count<<<(NE + 255) / 256, 256, 0, stream>>>(dst, deg);
    k_scan<<<1, 1024, 0, stream>>>(deg, rowp);
    hipMemcpyAsync(cur, rowp, (size_t)NN * 4, hipMemcpyDeviceToDevice, stream);
    k_scatter<<<(NE + 255) / 256, 256, 0, stream>>>(src, dst, cur, csrc);

    dim3 gg((NN + 63) / 64, (400 + 63) / 64);

    // layer 0: agg(x) -> lin0 -> BN/ReLU -> gemm(W2) -> BN/ReLU -> gemm(W3) -> pool
    k_agg0<<<(NN + 255) / 256, 256, 0, stream>>>(x, rowp, csrc, agg0);
    k_lin0<<<(int)(((long)NN * H + 255) / 256), 256, 0, stream>>>(agg0, c0_w1, c0_b1, bufh);
    k_stats<<<512, 256, 0, stream>>>(bufh, stats);
    k_finalize<<<2, 256, 0, stream>>>(stats, c0_g1, c0_be1, scale, shift);
    gemm400<true><<<gg, 256, 0, stream>>>(bufh, c0_w2, c0_b2, scale, shift, bufa, NN);
    k_stats<<<512, 256, 0, stream>>>(bufa, stats);
    k_finalize<<<2, 256, 0, stream>>>(stats, c0_g2, c0_be2, scale, shift);
    gemm400<true><<<gg, 256, 0, stream>>>(bufa, c0_w3, c0_b3, scale, shift, bufh, NN);
    k_pool<<<256, 256, 0, stream>>>(bufh, batch, pools, 0);

    // layers 1..2
    for (int l = 0; l < 2; ++l) {
        k_aggH<<<NN, 256, 0, stream>>>(bufh, rowp, csrc, bufa);
        gemm400<false><<<gg, 256, 0, stream>>>(bufa, cw1 + (size_t)l * H * H, cb1 + l * H,
                                               nullptr, nullptr, bufh, NN);
        k_stats<<<512, 256, 0, stream>>>(bufh, stats);
        k_finalize<<<2, 256, 0, stream>>>(stats, cg1 + l * H, cbe1 + l * H, scale, shift);
        gemm400<true><<<gg, 256, 0, stream>>>(bufh, cw2 + (size_t)l * H * H, cb2 + l * H,
                                              scale, shift, bufa, NN);
        k_stats<<<512, 256, 0, stream>>>(bufa, stats);
        k_finalize<<<2, 256, 0, stream>>>(stats, cg2 + l * H, cbe2 + l * H, scale, shift);
        gemm400<true><<<gg, 256, 0, stream>>>(bufa, cw3 + (size_t)l * H * H, cb3 + l * H,
                                              scale, shift, bufh, NN);
        k_pool<<<256, 256, 0, stream>>>(bufh, batch, pools, (l + 1) * H);
    }

    // readout
    k_head<<<NG, 256, 0, stream>>>(pools, lin1_w, lin1_b, lin2_w, lin2_b, (float*)d_out);
}

// Round 2
// 1784.928 us; speedup vs baseline: 1.6735x; 1.6735x over previous
//
#include <hip/hip_runtime.h>
#include <hip/hip_bf16.h>
#include <math.h>
#include <cstdint>

static constexpr int NN = 50000;   // nodes
static constexpr int NE = 400000;  // edges
static constexpr int MF = 4;       // input feature dim
static constexpr int H  = 400;     // hidden dim
static constexpr int NG = 128;     // graphs
static constexpr int NC = 10;      // classes
static constexpr float EPS = 1e-5f;

typedef __attribute__((ext_vector_type(8))) short bf16x8;
typedef __attribute__((ext_vector_type(4))) float f32x4;

__device__ __forceinline__ short f2bf(float f) {
    uint32_t u = __float_as_uint(f);
    uint32_t r = (u + 0x7FFFu + ((u >> 16) & 1u)) >> 16;
    return (short)r;
}

// ---------------- CSR build ----------------

__global__ void k_count(const int* __restrict__ dst, int* __restrict__ deg) {
    int e = blockIdx.x * blockDim.x + threadIdx.x;
    if (e < NE) atomicAdd(&deg[dst[e]], 1);
}

__global__ void k_scan(const int* __restrict__ deg, int* __restrict__ rowp) {
    __shared__ int sd[1024];
    __shared__ int srun;
    int t = threadIdx.x;
    if (t == 0) { srun = 0; rowp[0] = 0; }
    __syncthreads();
    for (int base = 0; base < NN; base += 1024) {
        int v = (base + t < NN) ? deg[base + t] : 0;
        sd[t] = v;
        __syncthreads();
        for (int off = 1; off < 1024; off <<= 1) {
            int x = (t >= off) ? sd[t - off] : 0;
            __syncthreads();
            sd[t] += x;
            __syncthreads();
        }
        if (base + t < NN) rowp[base + t + 1] = srun + sd[t];
        __syncthreads();
        if (t == 0) srun += sd[1023];
        __syncthreads();
    }
}

__global__ void k_scatter(const int* __restrict__ src, const int* __restrict__ dst,
                          int* __restrict__ cur, int* __restrict__ csrc) {
    int e = blockIdx.x * blockDim.x + threadIdx.x;
    if (e < NE) {
        int d = dst[e];
        int p = atomicAdd(&cur[d], 1);
        csrc[p] = src[e];
    }
}

// ---------------- aggregation ----------------

__global__ void k_agg0(const float* __restrict__ x, const int* __restrict__ rowp,
                       const int* __restrict__ csrc, float* __restrict__ out) {
    int n = blockIdx.x * blockDim.x + threadIdx.x;
    if (n >= NN) return;
    float4 acc = make_float4(0.f, 0.f, 0.f, 0.f);
    int b = rowp[n], e = rowp[n + 1];
    for (int p = b; p < e; ++p) {
        float4 v = ((const float4*)x)[csrc[p]];
        acc.x += v.x; acc.y += v.y; acc.z += v.z; acc.w += v.w;
    }
    ((float4*)out)[n] = acc;
}

__global__ __launch_bounds__(256) void k_aggH(const float* __restrict__ h,
                                              const int* __restrict__ rowp,
                                              const int* __restrict__ csrc,
                                              float* __restrict__ out) {
    int n = blockIdx.x;
    int t = threadIdx.x;
    int b = rowp[n], e = rowp[n + 1];
    float a0 = 0.f, a1 = 0.f;
    for (int p = b; p < e; ++p) {
        const float* r = h + (long)csrc[p] * H;
        a0 += r[t];
        if (t < H - 256) a1 += r[256 + t];
    }
    out[(long)n * H + t] = a0;
    if (t < H - 256) out[(long)n * H + 256 + t] = a1;
}

// ---------------- first linear (K = 4) ----------------

__global__ void k_lin0(const float* __restrict__ a4, const float* __restrict__ w,
                       const float* __restrict__ b, float* __restrict__ out) {
    long i = (long)blockIdx.x * blockDim.x + threadIdx.x;
    if (i >= (long)NN * H) return;
    int n = (int)(i / H), j = (int)(i - (long)n * H);
    float4 av = ((const float4*)a4)[n];
    float4 wv = ((const float4*)w)[j];
    out[i] = fmaf(av.x, wv.x, fmaf(av.y, wv.y, fmaf(av.z, wv.z, av.w * wv.w))) + b[j];
}

// ---------------- BN stats ----------------

__global__ __launch_bounds__(256) void k_stats(const float* __restrict__ z,
                                               float* __restrict__ stats) {
    int t = threadIdx.x;
    float s0 = 0.f, q0 = 0.f, s1 = 0.f, q1 = 0.f;
    for (int r = blockIdx.x; r < NN; r += gridDim.x) {
        const float* row = z + (long)r * H;
        float v = row[t];
        s0 += v; q0 += v * v;
        if (t < H - 256) {
            float u = row[256 + t];
            s1 += u; q1 += u * u;
        }
    }
    atomicAdd(&stats[t], s0);
    atomicAdd(&stats[H + t], q0);
    if (t < H - 256) {
        atomicAdd(&stats[256 + t], s1);
        atomicAdd(&stats[H + 256 + t], q1);
    }
}

__global__ void k_finalize(float* __restrict__ stats, const float* __restrict__ g,
                           const float* __restrict__ be, float* __restrict__ scale,
                           float* __restrict__ shift) {
    int j = blockIdx.x * blockDim.x + threadIdx.x;
    if (j >= H) return;
    float m = stats[j] / NN;
    float v = stats[H + j] / NN - m * m;
    v = fmaxf(v, 0.f);
    float rs = rsqrtf(v + EPS);
    float sc = g[j] * rs;
    scale[j] = sc;
    shift[j] = be[j] - m * sc;
    stats[j] = 0.f;          // self-clean for next use
    stats[H + j] = 0.f;
}

// ---------------- MFMA GEMM ----------------
// out[n][c] = sum_j f(A[n][j]) * W[c][j] + bias[c]
// f = relu(a*scale[j]+shift[j]) when TRANS, identity otherwise.
// A: M x 400 row-major fp32, W: 400 x 400 row-major fp32.
// Tile 128x80, BK=32 (K padded to 416 with zeros in W => pads contribute 0).
// 4 waves: wave w owns rows [w*32, w*32+32) x all 80 cols.
// LDS rows padded to 40 bf16 (80 B stride -> 2-way bank aliasing, free).

template <bool TRANS>
__global__ __launch_bounds__(256) void gemm_mfma(const float* __restrict__ A,
                                                 const float* __restrict__ W,
                                                 const float* __restrict__ bias,
                                                 const float* __restrict__ scale,
                                                 const float* __restrict__ shift,
                                                 float* __restrict__ out, int M) {
    constexpr int LDA = 40;
    __shared__ short As[2][128 * LDA];
    __shared__ short Bs[2][80 * LDA];

    const int t  = threadIdx.x;
    const int bm = blockIdx.x * 128;
    const int bn = blockIdx.y * 80;
    const int w  = t >> 6;
    const int l  = t & 63;

    f32x4 acc[2][5];
#pragma unroll
    for (int i = 0; i < 2; ++i)
#pragma unroll
        for (int c = 0; c < 5; ++c)
            acc[i][c] = (f32x4){0.f, 0.f, 0.f, 0.f};

    const int srow = t >> 3;          // 0..31
    const int skq  = (t & 7) * 4;     // 0,4,...,28

    auto stage = [&](int b, int k0) {
        const int k = k0 + skq;
        const bool kok = (k < 400);
        float4 sc = make_float4(0.f, 0.f, 0.f, 0.f);
        float4 sh = make_float4(0.f, 0.f, 0.f, 0.f);
        if (TRANS && kok) {
            sc = *(const float4*)(scale + k);
            sh = *(const float4*)(shift + k);
        }
        // A tile: 128 rows in 4 passes
#pragma unroll
        for (int p = 0; p < 4; ++p) {
            const int ar = p * 32 + srow;
            const int n  = bm + ar;
            float4 v = make_float4(0.f, 0.f, 0.f, 0.f);
            if (kok && n < M) v = *(const float4*)(A + (long)n * 400 + k);
            if (TRANS) {
                v.x = fmaxf(fmaf(v.x, sc.x, sh.x), 0.f);
                v.y = fmaxf(fmaf(v.y, sc.y, sh.y), 0.f);
                v.z = fmaxf(fmaf(v.z, sc.z, sh.z), 0.f);
                v.w = fmaxf(fmaf(v.w, sc.w, sh.w), 0.f);
            }
            uint32_t p01 = (uint32_t)(uint16_t)f2bf(v.x) | ((uint32_t)(uint16_t)f2bf(v.y) << 16);
            uint32_t p23 = (uint32_t)(uint16_t)f2bf(v.z) | ((uint32_t)(uint16_t)f2bf(v.w) << 16);
            *(uint2*)&As[b][ar * LDA + skq] = make_uint2(p01, p23);
        }
        // B tile: 80 rows in 3 passes (last partial); zero-pad k >= 400
#pragma unroll
        for (int p = 0; p < 3; ++p) {
            const int br = p * 32 + srow;
            if (br < 80) {
                float4 v = make_float4(0.f, 0.f, 0.f, 0.f);
                if (kok) v = *(const float4*)(W + (long)(bn + br) * 400 + k);
                uint32_t p01 = (uint32_t)(uint16_t)f2bf(v.x) | ((uint32_t)(uint16_t)f2bf(v.y) << 16);
                uint32_t p23 = (uint32_t)(uint16_t)f2bf(v.z) | ((uint32_t)(uint16_t)f2bf(v.w) << 16);
                *(uint2*)&Bs[b][br * LDA + skq] = make_uint2(p01, p23);
            }
        }
    };

    auto compute = [&](int b) {
        const short* ab = &As[b][(w * 32 + (l & 15)) * LDA + (l >> 4) * 8];
        const short* bb = &Bs[b][(l & 15) * LDA + (l >> 4) * 8];
        bf16x8 fa0 = *(const bf16x8*)ab;
        bf16x8 fa1 = *(const bf16x8*)(ab + 16 * LDA);
#pragma unroll
        for (int c = 0; c < 5; ++c) {
            bf16x8 fb = *(const bf16x8*)(bb + c * 16 * LDA);
            acc[0][c] = __builtin_amdgcn_mfma_f32_16x16x32_bf16(fa0, fb, acc[0][c], 0, 0, 0);
            acc[1][c] = __builtin_amdgcn_mfma_f32_16x16x32_bf16(fa1, fb, acc[1][c], 0, 0, 0);
        }
    };

    constexpr int NK = 13;   // ceil(400/32)
    stage(0, 0);
    __syncthreads();
#pragma unroll 1
    for (int s = 0; s < NK; ++s) {
        if (s + 1 < NK) stage((s + 1) & 1, (s + 1) * 32);
        compute(s & 1);
        __syncthreads();
    }

    // epilogue: C/D layout col=lane&15, row=(lane>>4)*4+reg
#pragma unroll
    for (int i = 0; i < 2; ++i) {
        const int rbase = bm + w * 32 + i * 16 + (l >> 4) * 4;
#pragma unroll
        for (int c = 0; c < 5; ++c) {
            const int col = bn + c * 16 + (l & 15);
            const float bv = bias[col];
#pragma unroll
            for (int r = 0; r < 4; ++r) {
                const int row = rbase + r;
                if (row < M) out[(long)row * 400 + col] = acc[i][c][r] + bv;
            }
        }
    }
}

// ---------------- pooling (batch is sorted) ----------------

__global__ __launch_bounds__(256) void k_pool(const float* __restrict__ h,
                                              const int* __restrict__ batch,
                                              float* __restrict__ pools, int off) {
    int t = threadIdx.x;
    int rows = (NN + gridDim.x - 1) / gridDim.x;
    int r0 = blockIdx.x * rows;
    int r1 = min(r0 + rows, NN);
    if (r0 >= r1) return;
    float a0 = 0.f, a1 = 0.f;
    int gp = batch[r0];
    for (int r = r0; r < r1; ++r) {
        int gg = batch[r];
        if (gg != gp) {
            atomicAdd(&pools[(long)gp * (3 * H) + off + t], a0);
            if (t < H - 256) atomicAdd(&pools[(long)gp * (3 * H) + off + 256 + t], a1);
            a0 = 0.f; a1 = 0.f; gp = gg;
        }
        const float* row = h + (long)r * H;
        a0 += row[t];
        if (t < H - 256) a1 += row[256 + t];
    }
    atomicAdd(&pools[(long)gp * (3 * H) + off + t], a0);
    if (t < H - 256) atomicAdd(&pools[(long)gp * (3 * H) + off + 256 + t], a1);
}

// ---------------- readout head ----------------

__global__ __launch_bounds__(256) void k_head(const float* __restrict__ pools,
                                              const float* __restrict__ w1,
                                              const float* __restrict__ b1,
                                              const float* __restrict__ w2,
                                              const float* __restrict__ b2,
                                              float* __restrict__ out) {
    __shared__ float xg[1200];
    __shared__ float zz[600];
    __shared__ float lg[16];
    int g = blockIdx.x, t = threadIdx.x;
    for (int i = t; i < 1200; i += 256) xg[i] = pools[(long)g * 1200 + i];
    __syncthreads();
    for (int j = t; j < 600; j += 256) {
        float s = b1[j];
        const float* wr = w1 + (long)j * 1200;
        for (int k = 0; k < 1200; k += 4) {
            s = fmaf(xg[k], wr[k], s);
            s = fmaf(xg[k + 1], wr[k + 1], s);
            s = fmaf(xg[k + 2], wr[k + 2], s);
            s = fmaf(xg[k + 3], wr[k + 3], s);
        }
        zz[j] = fmaxf(s, 0.f);
    }
    __syncthreads();
    if (t < NC) {
        float s = b2[t];
        const float* wr = w2 + t * 600;
        for (int k = 0; k < 600; ++k) s = fmaf(zz[k], wr[k], s);
        lg[t] = s;
    }
    __syncthreads();
    if (t == 0) {
        float mx = lg[0];
        for (int c = 1; c < NC; ++c) mx = fmaxf(mx, lg[c]);
        float se = 0.f;
        for (int c = 0; c < NC; ++c) se += expf(lg[c] - mx);
        float l = logf(se);
        for (int c = 0; c < NC; ++c) out[(long)g * NC + c] = lg[c] - mx - l;
    }
}

// ---------------- launch ----------------

extern "C" void kernel_launch(void* const* d_in, const int* in_sizes, int n_in,
                              void* d_out, int out_size, void* d_ws, size_t ws_size,
                              hipStream_t stream) {
    const float* x      = (const float*)d_in[0];
    const int*   ei     = (const int*)d_in[1];
    const int*   batch  = (const int*)d_in[2];
    const float* c0_w1  = (const float*)d_in[4];
    const float* c0_b1  = (const float*)d_in[5];
    const float* c0_g1  = (const float*)d_in[6];
    const float* c0_be1 = (const float*)d_in[7];
    const float* c0_w2  = (const float*)d_in[8];
    const float* c0_b2  = (const float*)d_in[9];
    const float* c0_g2  = (const float*)d_in[10];
    const float* c0_be2 = (const float*)d_in[11];
    const float* c0_w3  = (const float*)d_in[12];
    const float* c0_b3  = (const float*)d_in[13];
    const float* cw1    = (const float*)d_in[14];
    const float* cb1    = (const float*)d_in[15];
    const float* cg1    = (const float*)d_in[16];
    const float* cbe1   = (const float*)d_in[17];
    const float* cw2    = (const float*)d_in[18];
    const float* cb2    = (const float*)d_in[19];
    const float* cg2    = (const float*)d_in[20];
    const float* cbe2   = (const float*)d_in[21];
    const float* cw3    = (const float*)d_in[22];
    const float* cb3    = (const float*)d_in[23];
    const float* lin1_w = (const float*)d_in[24];
    const float* lin1_b = (const float*)d_in[25];
    const float* lin2_w = (const float*)d_in[26];
    const float* lin2_b = (const float*)d_in[27];

    const int* src = ei;
    const int* dst = ei + NE;

    char* ws = (char*)d_ws;
    size_t off = 0;
    auto alloc = [&](size_t bytes) {
        void* p = ws + off;
        off += (bytes + 255) & ~(size_t)255;
        return p;
    };
    float* bufh  = (float*)alloc((size_t)NN * H * 4);
    float* bufa  = (float*)alloc((size_t)NN * H * 4);
    float* agg0  = (float*)alloc((size_t)NN * MF * 4);
    float* stats = (float*)alloc(2 * H * 4);
    float* scale = (float*)alloc(H * 4);
    float* shift = (float*)alloc(H * 4);
    float* pools = (float*)alloc((size_t)NG * 3 * H * 4);
    int*   deg   = (int*)alloc((size_t)NN * 4);
    int*   rowp  = (int*)alloc((size_t)(NN + 1) * 4);
    int*   cur   = (int*)alloc((size_t)NN * 4);
    int*   csrc  = (int*)alloc((size_t)NE * 4);

    hipMemsetAsync(deg, 0, (size_t)NN * 4, stream);
    hipMemsetAsync(stats, 0, 2 * H * 4, stream);
    hipMemsetAsync(pools, 0, (size_t)NG * 3 * H * 4, stream);

    // CSR build
    k_count<<<(NE + 255) / 256, 256, 0, stream>>>(dst, deg);
    k_scan<<<1, 1024, 0, stream>>>(deg, rowp);
    hipMemcpyAsync(cur, rowp, (size_t)NN * 4, hipMemcpyDeviceToDevice, stream);
    k_scatter<<<(NE + 255) / 256, 256, 0, stream>>>(src, dst, cur, csrc);

    dim3 gg((NN + 127) / 128, 5);

    // layer 0: agg(x) -> lin0 -> BN/ReLU -> gemm(W2) -> BN/ReLU -> gemm(W3) -> pool
    k_agg0<<<(NN + 255) / 256, 256, 0, stream>>>(x, rowp, csrc, agg0);
    k_lin0<<<(int)(((long)NN * H + 255) / 256), 256, 0, stream>>>(agg0, c0_w1, c0_b1, bufh);
    k_stats<<<512, 256, 0, stream>>>(bufh, stats);
    k_finalize<<<2, 256, 0, stream>>>(stats, c0_g1, c0_be1, scale, shift);
    gemm_mfma<true><<<gg, 256, 0, stream>>>(bufh, c0_w2, c0_b2, scale, shift, bufa, NN);
    k_stats<<<512, 256, 0, stream>>>(bufa, stats);
    k_finalize<<<2, 256, 0, stream>>>(stats, c0_g2, c0_be2, scale, shift);
    gemm_mfma<true><<<gg, 256, 0, stream>>>(bufa, c0_w3, c0_b3, scale, shift, bufh, NN);
    k_pool<<<256, 256, 0, stream>>>(bufh, batch, pools, 0);

    // layers 1..2
    for (int l = 0; l < 2; ++l) {
        k_aggH<<<NN, 256, 0, stream>>>(bufh, rowp, csrc, bufa);
        gemm_mfma<false><<<gg, 256, 0, stream>>>(bufa, cw1 + (size_t)l * H * H, cb1 + l * H,
                                                 nullptr, nullptr, bufh, NN);
        k_stats<<<512, 256, 0, stream>>>(bufh, stats);
        k_finalize<<<2, 256, 0, stream>>>(stats, cg1 + l * H, cbe1 + l * H, scale, shift);
        gemm_mfma<true><<<gg, 256, 0, stream>>>(bufh, cw2 + (size_t)l * H * H, cb2 + l * H,
                                                scale, shift, bufa, NN);
        k_stats<<<512, 256, 0, stream>>>(bufa, stats);
        k_finalize<<<2, 256, 0, stream>>>(stats, cg2 + l * H, cbe2 + l * H, scale, shift);
        gemm_mfma<true><<<gg, 256, 0, stream>>>(bufa, cw3 + (size_t)l * H * H, cb3 + l * H,
                                                scale, shift, bufh, NN);
        k_pool<<<256, 256, 0, stream>>>(bufh, batch, pools, (l + 1) * H);
    }

    // readout
    k_head<<<NG, 256, 0, stream>>>(pools, lin1_w, lin1_b, lin2_w, lin2_b, (float*)d_out);
}

// Round 3
// 1165.366 us; speedup vs baseline: 2.5632x; 1.5316x over previous
//
#include <hip/hip_runtime.h>
#include <hip/hip_bf16.h>
#include <math.h>
#include <cstdint>

static constexpr int NN = 50000;   // nodes
static constexpr int NE = 400000;  // edges
static constexpr int H  = 400;     // hidden dim
static constexpr int NG = 128;     // graphs
static constexpr int NC = 10;      // classes
static constexpr float EPS = 1e-5f;

typedef unsigned short u16;
typedef __attribute__((ext_vector_type(8))) unsigned short u16x8;
typedef __attribute__((ext_vector_type(4))) unsigned short u16x4;
typedef __attribute__((ext_vector_type(8))) short bf16x8;
typedef __attribute__((ext_vector_type(4))) float f32x4;

__device__ __forceinline__ float bf2f(u16 u) {
    return __uint_as_float(((uint32_t)u) << 16);
}
__device__ __forceinline__ u16 f2bf(float f) {
    uint32_t u = __float_as_uint(f);
    return (u16)((u + 0x7FFFu + ((u >> 16) & 1u)) >> 16);
}

// ---------------- CSR build ----------------

__global__ void k_count(const int* __restrict__ dst, int* __restrict__ deg) {
    int e = blockIdx.x * blockDim.x + threadIdx.x;
    if (e < NE) atomicAdd(&deg[dst[e]], 1);
}

__global__ void k_scan(const int* __restrict__ deg, int* __restrict__ rowp) {
    __shared__ int sd[1024];
    __shared__ int srun;
    int t = threadIdx.x;
    if (t == 0) { srun = 0; rowp[0] = 0; }
    __syncthreads();
    for (int base = 0; base < NN; base += 1024) {
        int v = (base + t < NN) ? deg[base + t] : 0;
        sd[t] = v;
        __syncthreads();
        for (int off = 1; off < 1024; off <<= 1) {
            int x = (t >= off) ? sd[t - off] : 0;
            __syncthreads();
            sd[t] += x;
            __syncthreads();
        }
        if (base + t < NN) rowp[base + t + 1] = srun + sd[t];
        __syncthreads();
        if (t == 0) srun += sd[1023];
        __syncthreads();
    }
}

__global__ void k_scatter(const int* __restrict__ src, const int* __restrict__ dst,
                          int* __restrict__ cur, int* __restrict__ csrc) {
    int e = blockIdx.x * blockDim.x + threadIdx.x;
    if (e < NE) {
        int d = dst[e];
        int p = atomicAdd(&cur[d], 1);
        csrc[p] = src[e];
    }
}

// ---------------- weight fp32 -> bf16 ----------------

__global__ void k_cvtw(const float* __restrict__ src, u16* __restrict__ dst, int n4) {
    int i = blockIdx.x * blockDim.x + threadIdx.x;
    if (i >= n4) return;
    float4 v = ((const float4*)src)[i];
    u16x4 o;
    o[0] = f2bf(v.x); o[1] = f2bf(v.y); o[2] = f2bf(v.z); o[3] = f2bf(v.w);
    *(u16x4*)(dst + i * 4) = o;
}

// ---------------- aggregation ----------------

__global__ void k_agg0(const float* __restrict__ x, const int* __restrict__ rowp,
                       const int* __restrict__ csrc, float* __restrict__ out) {
    int n = blockIdx.x * blockDim.x + threadIdx.x;
    if (n >= NN) return;
    float4 acc = make_float4(0.f, 0.f, 0.f, 0.f);
    int b = rowp[n], e = rowp[n + 1];
    for (int p = b; p < e; ++p) {
        float4 v = ((const float4*)x)[csrc[p]];
        acc.x += v.x; acc.y += v.y; acc.z += v.z; acc.w += v.w;
    }
    ((float4*)out)[n] = acc;
}

// one wave per node; lanes 0..49 each own 8 contiguous features
__global__ __launch_bounds__(256) void k_aggH(const u16* __restrict__ h,
                                              const int* __restrict__ rowp,
                                              const int* __restrict__ csrc,
                                              u16* __restrict__ out) {
    int n = (blockIdx.x << 2) + (threadIdx.x >> 6);
    if (n >= NN) return;
    int l = threadIdx.x & 63;
    if (l >= 50) return;
    int b = rowp[n], e = rowp[n + 1];
    float acc[8] = {0.f, 0.f, 0.f, 0.f, 0.f, 0.f, 0.f, 0.f};
    for (int p = b; p < e; ++p) {
        const u16* r = h + (long)csrc[p] * H + l * 8;
        u16x8 v = *(const u16x8*)r;
#pragma unroll
        for (int q = 0; q < 8; ++q) acc[q] += bf2f(v[q]);
    }
    u16x8 o;
#pragma unroll
    for (int q = 0; q < 8; ++q) o[q] = f2bf(acc[q]);
    *(u16x8*)(out + (long)n * H + l * 8) = o;
}

// ---------------- first linear (K = 4), bf16 out ----------------

__global__ void k_lin0(const float* __restrict__ a4, const float* __restrict__ w,
                       const float* __restrict__ b, u16* __restrict__ out) {
    long i = (long)blockIdx.x * blockDim.x + threadIdx.x;   // over NN*100
    if (i >= (long)NN * 100) return;
    int n = (int)(i / 100), q = (int)(i - (long)n * 100);
    int j0 = q * 4;
    float4 av = ((const float4*)a4)[n];
    u16x4 o;
#pragma unroll
    for (int jj = 0; jj < 4; ++jj) {
        float4 wv = ((const float4*)w)[j0 + jj];
        float s = fmaf(av.x, wv.x, fmaf(av.y, wv.y, fmaf(av.z, wv.z, av.w * wv.w)));
        o[jj] = f2bf(s + b[j0 + jj]);
    }
    *(u16x4*)(out + (long)n * H + j0) = o;
}

// ---------------- BN stats over bf16 buffer (only needed after lin0) ----------------

__global__ __launch_bounds__(256) void k_statsb(const u16* __restrict__ z,
                                                float* __restrict__ stats) {
    int t = threadIdx.x;
    float s0 = 0.f, q0 = 0.f, s1 = 0.f, q1 = 0.f;
    for (int r = blockIdx.x; r < NN; r += gridDim.x) {
        const u16* row = z + (long)r * H;
        float v = bf2f(row[t]);
        s0 += v; q0 += v * v;
        if (t < H - 256) {
            float u = bf2f(row[256 + t]);
            s1 += u; q1 += u * u;
        }
    }
    atomicAdd(&stats[t], s0);
    atomicAdd(&stats[H + t], q0);
    if (t < H - 256) {
        atomicAdd(&stats[256 + t], s1);
        atomicAdd(&stats[H + 256 + t], q1);
    }
}

__global__ void k_finalize(float* __restrict__ stats, const float* __restrict__ g,
                           const float* __restrict__ be, float* __restrict__ scale,
                           float* __restrict__ shift) {
    int j = blockIdx.x * blockDim.x + threadIdx.x;
    if (j >= H) return;
    float m = stats[j] / NN;
    float v = stats[H + j] / NN - m * m;
    v = fmaxf(v, 0.f);
    float rs = rsqrtf(v + EPS);
    float sc = g[j] * rs;
    scale[j] = sc;
    shift[j] = be[j] - m * sc;
    stats[j] = 0.f;          // self-clean for next use
    stats[H + j] = 0.f;
}

// ---------------- MFMA GEMM (bf16 in / bf16 out, optional BN+ReLU on A,
//                  optional fused column stats of the fp32 output) ----------------
// out[n][c] = sum_j f(A[n][j]) * W[c][j] + bias[c]
// A: M x 400 bf16 row-major. W: 400 x 400 bf16 row-major.
// Tile 128x80, BK=32, grid (5, ceil(M/128)) -> col-band fastest (A-panel L2/L3 reuse).

template <bool TRANS, bool STATS>
__global__ __launch_bounds__(256) void gemm_mfma(const u16* __restrict__ A,
                                                 const u16* __restrict__ W,
                                                 const float* __restrict__ bias,
                                                 const float* __restrict__ scale,
                                                 const float* __restrict__ shift,
                                                 u16* __restrict__ out,
                                                 float* __restrict__ stats, int M) {
    constexpr int LDA = 40;
    __shared__ u16 As[2][128 * LDA];
    __shared__ u16 Bs[2][80 * LDA];
    __shared__ float sst[160];

    const int t  = threadIdx.x;
    const int bn = blockIdx.x * 80;
    const int bm = blockIdx.y * 128;
    const int w  = t >> 6;
    const int l  = t & 63;

    f32x4 acc[2][5];
#pragma unroll
    for (int i = 0; i < 2; ++i)
#pragma unroll
        for (int c = 0; c < 5; ++c)
            acc[i][c] = (f32x4){0.f, 0.f, 0.f, 0.f};

    auto stage = [&](int b, int k0) {
        // A tile: 128 rows x 32 k, 512 segs of 8 elems -> 2 passes
#pragma unroll
        for (int pass = 0; pass < 2; ++pass) {
            int seg = pass * 256 + t;
            int row = seg >> 2, kq = seg & 3;
            int k = k0 + kq * 8;
            int n = bm + row;
            u16x8 v = {0, 0, 0, 0, 0, 0, 0, 0};
            if (k < 400 && n < M) v = *(const u16x8*)(A + (long)n * H + k);
            if (TRANS && k < 400) {
                float4 sc0 = *(const float4*)(scale + k);
                float4 sc1 = *(const float4*)(scale + k + 4);
                float4 sh0 = *(const float4*)(shift + k);
                float4 sh1 = *(const float4*)(shift + k + 4);
                float f0 = fmaxf(fmaf(bf2f(v[0]), sc0.x, sh0.x), 0.f);
                float f1 = fmaxf(fmaf(bf2f(v[1]), sc0.y, sh0.y), 0.f);
                float f2 = fmaxf(fmaf(bf2f(v[2]), sc0.z, sh0.z), 0.f);
                float f3 = fmaxf(fmaf(bf2f(v[3]), sc0.w, sh0.w), 0.f);
                float f4 = fmaxf(fmaf(bf2f(v[4]), sc1.x, sh1.x), 0.f);
                float f5 = fmaxf(fmaf(bf2f(v[5]), sc1.y, sh1.y), 0.f);
                float f6 = fmaxf(fmaf(bf2f(v[6]), sc1.z, sh1.z), 0.f);
                float f7 = fmaxf(fmaf(bf2f(v[7]), sc1.w, sh1.w), 0.f);
                v[0] = f2bf(f0); v[1] = f2bf(f1); v[2] = f2bf(f2); v[3] = f2bf(f3);
                v[4] = f2bf(f4); v[5] = f2bf(f5); v[6] = f2bf(f6); v[7] = f2bf(f7);
            }
            *(u16x8*)&As[b][row * LDA + kq * 8] = v;
        }
        // B tile: 80 rows x 32 k, 320 segs -> 2 passes (second partial)
#pragma unroll
        for (int pass = 0; pass < 2; ++pass) {
            int seg = pass * 256 + t;
            if (seg < 320) {
                int row = seg >> 2, kq = seg & 3;
                int k = k0 + kq * 8;
                u16x8 v = {0, 0, 0, 0, 0, 0, 0, 0};
                if (k < 400) v = *(const u16x8*)(W + (long)(bn + row) * H + k);
                *(u16x8*)&Bs[b][row * LDA + kq * 8] = v;
            }
        }
    };

    auto compute = [&](int b) {
        const u16* ab = &As[b][(w * 32 + (l & 15)) * LDA + (l >> 4) * 8];
        const u16* bb = &Bs[b][(l & 15) * LDA + (l >> 4) * 8];
        bf16x8 fa0 = *(const bf16x8*)ab;
        bf16x8 fa1 = *(const bf16x8*)(ab + 16 * LDA);
#pragma unroll
        for (int c = 0; c < 5; ++c) {
            bf16x8 fb = *(const bf16x8*)(bb + c * 16 * LDA);
            acc[0][c] = __builtin_amdgcn_mfma_f32_16x16x32_bf16(fa0, fb, acc[0][c], 0, 0, 0);
            acc[1][c] = __builtin_amdgcn_mfma_f32_16x16x32_bf16(fa1, fb, acc[1][c], 0, 0, 0);
        }
    };

    if (STATS && t < 160) sst[t] = 0.f;

    constexpr int NK = 13;   // ceil(400/32)
    stage(0, 0);
    __syncthreads();
#pragma unroll 1
    for (int s = 0; s < NK; ++s) {
        if (s + 1 < NK) stage((s + 1) & 1, (s + 1) * 32);
        compute(s & 1);
        __syncthreads();
    }

    // epilogue: C/D layout col=lane&15, row=(lane>>4)*4+reg
    float ssum[5], sqq[5];
#pragma unroll
    for (int c = 0; c < 5; ++c) { ssum[c] = 0.f; sqq[c] = 0.f; }
#pragma unroll
    for (int i = 0; i < 2; ++i) {
        const int rbase = bm + w * 32 + i * 16 + (l >> 4) * 4;
#pragma unroll
        for (int c = 0; c < 5; ++c) {
            const int col = bn + c * 16 + (l & 15);
            const float bv = bias[col];
#pragma unroll
            for (int r = 0; r < 4; ++r) {
                const int row = rbase + r;
                if (row < M) {
                    float z = acc[i][c][r] + bv;
                    out[(long)row * H + col] = f2bf(z);
                    if (STATS) { ssum[c] += z; sqq[c] += z * z; }
                }
            }
        }
    }
    if (STATS) {
#pragma unroll
        for (int c = 0; c < 5; ++c) {
            ssum[c] += __shfl_xor(ssum[c], 16); ssum[c] += __shfl_xor(ssum[c], 32);
            sqq[c]  += __shfl_xor(sqq[c], 16);  sqq[c]  += __shfl_xor(sqq[c], 32);
        }
        if (l < 16) {
#pragma unroll
            for (int c = 0; c < 5; ++c) {
                atomicAdd(&sst[c * 16 + l], ssum[c]);
                atomicAdd(&sst[80 + c * 16 + l], sqq[c]);
            }
        }
        __syncthreads();
        if (t < 80)       atomicAdd(&stats[bn + t], sst[t]);
        else if (t < 160) atomicAdd(&stats[H + bn + (t - 80)], sst[t]);
    }
}

// ---------------- pooling (batch sorted), bf16 input ----------------

__global__ __launch_bounds__(256) void k_pool(const u16* __restrict__ h,
                                              const int* __restrict__ batch,
                                              float* __restrict__ pools, int off) {
    int t = threadIdx.x;
    int rows = (NN + gridDim.x - 1) / gridDim.x;
    int r0 = blockIdx.x * rows;
    int r1 = min(r0 + rows, NN);
    if (r0 >= r1) return;
    float a0 = 0.f, a1 = 0.f;
    int gp = batch[r0];
    for (int r = r0; r < r1; ++r) {
        int gg = batch[r];
        if (gg != gp) {
            atomicAdd(&pools[(long)gp * (3 * H) + off + t], a0);
            if (t < H - 256) atomicAdd(&pools[(long)gp * (3 * H) + off + 256 + t], a1);
            a0 = 0.f; a1 = 0.f; gp = gg;
        }
        const u16* row = h + (long)r * H;
        a0 += bf2f(row[t]);
        if (t < H - 256) a1 += bf2f(row[256 + t]);
    }
    atomicAdd(&pools[(long)gp * (3 * H) + off + t], a0);
    if (t < H - 256) atomicAdd(&pools[(long)gp * (3 * H) + off + 256 + t], a1);
}

// ---------------- readout: lin1 (wave per output), lin2 + log_softmax ----------------

__global__ __launch_bounds__(256) void k_lin1(const float* __restrict__ pools,
                                              const float* __restrict__ w1,
                                              const float* __restrict__ b1,
                                              float* __restrict__ zz) {
    int gid = blockIdx.x * 4 + (threadIdx.x >> 6);
    int l = threadIdx.x & 63;
    int g = gid / 600, j = gid - g * 600;
    if (g >= NG) return;
    const float4* xr = (const float4*)(pools + (long)g * 1200);
    const float4* wr = (const float4*)(w1 + (long)j * 1200);
    float s = 0.f;
    for (int q = l; q < 300; q += 64) {
        float4 a = xr[q], b = wr[q];
        s = fmaf(a.x, b.x, s); s = fmaf(a.y, b.y, s);
        s = fmaf(a.z, b.z, s); s = fmaf(a.w, b.w, s);
    }
#pragma unroll
    for (int o = 32; o; o >>= 1) s += __shfl_xor(s, o);
    if (l == 0) zz[(long)g * 600 + j] = fmaxf(s + b1[j], 0.f);
}

__global__ __launch_bounds__(64) void k_lin2(const float* __restrict__ zz,
                                             const float* __restrict__ w2,
                                             const float* __restrict__ b2,
                                             float* __restrict__ out) {
    int g = blockIdx.x;
    int l = threadIdx.x;
    float p[NC];
#pragma unroll
    for (int c = 0; c < NC; ++c) p[c] = 0.f;
    for (int k = l; k < 600; k += 64) {
        float zv = zz[(long)g * 600 + k];
#pragma unroll
        for (int c = 0; c < NC; ++c) p[c] = fmaf(zv, w2[c * 600 + k], p[c]);
    }
#pragma unroll
    for (int c = 0; c < NC; ++c)
#pragma unroll
        for (int o = 32; o; o >>= 1) p[c] += __shfl_xor(p[c], o);
    if (l == 0) {
        float lg[NC];
        float mx = -1e30f;
#pragma unroll
        for (int c = 0; c < NC; ++c) { lg[c] = p[c] + b2[c]; mx = fmaxf(mx, lg[c]); }
        float se = 0.f;
#pragma unroll
        for (int c = 0; c < NC; ++c) se += expf(lg[c] - mx);
        float lse = logf(se);
#pragma unroll
        for (int c = 0; c < NC; ++c) out[(long)g * NC + c] = lg[c] - mx - lse;
    }
}

// ---------------- launch ----------------

extern "C" void kernel_launch(void* const* d_in, const int* in_sizes, int n_in,
                              void* d_out, int out_size, void* d_ws, size_t ws_size,
                              hipStream_t stream) {
    const float* x      = (const float*)d_in[0];
    const int*   ei     = (const int*)d_in[1];
    const int*   batch  = (const int*)d_in[2];
    const float* c0_w1  = (const float*)d_in[4];
    const float* c0_b1  = (const float*)d_in[5];
    const float* c0_g1  = (const float*)d_in[6];
    const float* c0_be1 = (const float*)d_in[7];
    const float* c0_w2  = (const float*)d_in[8];
    const float* c0_b2  = (const float*)d_in[9];
    const float* c0_g2  = (const float*)d_in[10];
    const float* c0_be2 = (const float*)d_in[11];
    const float* c0_w3  = (const float*)d_in[12];
    const float* c0_b3  = (const float*)d_in[13];
    const float* cw1    = (const float*)d_in[14];
    const float* cb1    = (const float*)d_in[15];
    const float* cg1    = (const float*)d_in[16];
    const float* cbe1   = (const float*)d_in[17];
    const float* cw2    = (const float*)d_in[18];
    const float* cb2    = (const float*)d_in[19];
    const float* cg2    = (const float*)d_in[20];
    const float* cbe2   = (const float*)d_in[21];
    const float* cw3    = (const float*)d_in[22];
    const float* cb3    = (const float*)d_in[23];
    const float* lin1_w = (const float*)d_in[24];
    const float* lin1_b = (const float*)d_in[25];
    const float* lin2_w = (const float*)d_in[26];
    const float* lin2_b = (const float*)d_in[27];

    const int* src = ei;
    const int* dst = ei + NE;

    char* ws = (char*)d_ws;
    size_t off = 0;
    auto alloc = [&](size_t bytes) {
        void* p = ws + off;
        off += (bytes + 255) & ~(size_t)255;
        return p;
    };
    u16*   bufh  = (u16*)alloc((size_t)NN * H * 2);
    u16*   bufa  = (u16*)alloc((size_t)NN * H * 2);
    float* agg0  = (float*)alloc((size_t)NN * 4 * 4);
    float* stats = (float*)alloc(2 * H * 4);
    float* scale = (float*)alloc(H * 4);
    float* shift = (float*)alloc(H * 4);
    float* pools = (float*)alloc((size_t)NG * 3 * H * 4);
    float* zz    = (float*)alloc((size_t)NG * 600 * 4);
    u16*   w2b_0 = (u16*)alloc((size_t)H * H * 2);   // c0_w2
    u16*   w3b_0 = (u16*)alloc((size_t)H * H * 2);   // c0_w3
    u16*   w1b   = (u16*)alloc((size_t)2 * H * H * 2);
    u16*   w2b   = (u16*)alloc((size_t)2 * H * H * 2);
    u16*   w3b   = (u16*)alloc((size_t)2 * H * H * 2);
    int*   deg   = (int*)alloc((size_t)NN * 4);
    int*   rowp  = (int*)alloc((size_t)(NN + 1) * 4);
    int*   cur   = (int*)alloc((size_t)NN * 4);
    int*   csrc  = (int*)alloc((size_t)NE * 4);

    hipMemsetAsync(deg, 0, (size_t)NN * 4, stream);
    hipMemsetAsync(stats, 0, 2 * H * 4, stream);
    hipMemsetAsync(pools, 0, (size_t)NG * 3 * H * 4, stream);

    // weights -> bf16 (once per launch; cheap)
    k_cvtw<<<(H * H / 4 + 255) / 256, 256, 0, stream>>>(c0_w2, w2b_0, H * H / 4);
    k_cvtw<<<(H * H / 4 + 255) / 256, 256, 0, stream>>>(c0_w3, w3b_0, H * H / 4);
    k_cvtw<<<(2 * H * H / 4 + 255) / 256, 256, 0, stream>>>(cw1, w1b, 2 * H * H / 4);
    k_cvtw<<<(2 * H * H / 4 + 255) / 256, 256, 0, stream>>>(cw2, w2b, 2 * H * H / 4);
    k_cvtw<<<(2 * H * H / 4 + 255) / 256, 256, 0, stream>>>(cw3, w3b, 2 * H * H / 4);

    // CSR build
    k_count<<<(NE + 255) / 256, 256, 0, stream>>>(dst, deg);
    k_scan<<<1, 1024, 0, stream>>>(deg, rowp);
    hipMemcpyAsync(cur, rowp, (size_t)NN * 4, hipMemcpyDeviceToDevice, stream);
    k_scatter<<<(NE + 255) / 256, 256, 0, stream>>>(src, dst, cur, csrc);

    dim3 gg(5, (NN + 127) / 128);

    // layer 0
    k_agg0<<<(NN + 255) / 256, 256, 0, stream>>>(x, rowp, csrc, agg0);
    k_lin0<<<(int)(((long)NN * 100 + 255) / 256), 256, 0, stream>>>(agg0, c0_w1, c0_b1, bufh);
    k_statsb<<<512, 256, 0, stream>>>(bufh, stats);
    k_finalize<<<2, 256, 0, stream>>>(stats, c0_g1, c0_be1, scale, shift);
    gemm_mfma<true, true><<<gg, 256, 0, stream>>>(bufh, w2b_0, c0_b2, scale, shift, bufa, stats, NN);
    k_finalize<<<2, 256, 0, stream>>>(stats, c0_g2, c0_be2, scale, shift);
    gemm_mfma<true, false><<<gg, 256, 0, stream>>>(bufa, w3b_0, c0_b3, scale, shift, bufh, stats, NN);
    k_pool<<<256, 256, 0, stream>>>(bufh, batch, pools, 0);

    // layers 1..2
    for (int l = 0; l < 2; ++l) {
        k_aggH<<<(NN + 3) / 4, 256, 0, stream>>>(bufh, rowp, csrc, bufa);
        gemm_mfma<false, true><<<gg, 256, 0, stream>>>(bufa, w1b + (size_t)l * H * H,
                                                       cb1 + l * H, nullptr, nullptr,
                                                       bufh, stats, NN);
        k_finalize<<<2, 256, 0, stream>>>(stats, cg1 + l * H, cbe1 + l * H, scale, shift);
        gemm_mfma<true, true><<<gg, 256, 0, stream>>>(bufh, w2b + (size_t)l * H * H,
                                                      cb2 + l * H, scale, shift,
                                                      bufa, stats, NN);
        k_finalize<<<2, 256, 0, stream>>>(stats, cg2 + l * H, cbe2 + l * H, scale, shift);
        gemm_mfma<true, false><<<gg, 256, 0, stream>>>(bufa, w3b + (size_t)l * H * H,
                                                       cb3 + l * H, scale, shift,
                                                       bufh, stats, NN);
        k_pool<<<256, 256, 0, stream>>>(bufh, batch, pools, (l + 1) * H);
    }

    // readout
    k_lin1<<<(NG * 600 + 3) / 4, 256, 0, stream>>>(pools, lin1_w, lin1_b, zz);
    k_lin2<<<NG, 64, 0, stream>>>(zz, lin2_w, lin2_b, (float*)d_out);
}